// Round 3
// baseline (69.135 us; speedup 1.0000x reference)
//
#include <hip/hip_runtime.h>

// Chamfer loss: predict_pc [B=4, 3, N=8192] f32, gt_pc [B, 3, N] f32.
// loss = sum_gt min_pred d / B + sum_pred min_gt d / B
//
// d2 = |p|^2 + |g|^2 - 2 p.g ; for fixed query p:
//   min_g d2 = |p|^2 - 2 * max_g s,  s = p.g - 0.5|g|^2
// Inner loop processes 2 opposite points per step with packed fp32
// (v_pk_fma_f32) and folds both into the running max with v_max3_f32:
// 2 VALU instructions per (query, point) pair.
// min(sqrt(x)) = sqrt(min(x)) -> sqrt only at the end.
// Cross-block merge via int atomicMin on non-negative floats (exact,
// order-independent => deterministic). Two-stage tree reduction for the sum.

#define BQ 256          // threads per block
#define QPT 4           // query points per thread (independent dep-chains)
#define QTILE (BQ*QPT)  // 1024 queries per block
#define GCHUNK 256      // opposite points staged per block
#define RBLKS 64        // stage-1 reduction blocks

typedef float v2f __attribute__((ext_vector_type(2)));

// d = a*b + c elementwise on 2 packed fp32 (guaranteed v_pk_fma_f32)
#define PKFMA(d, a, b, c) \
    asm("v_pk_fma_f32 %0, %1, %2, %3" : "=v"(d) : "v"(a), "v"(b), "v"(c))

__global__ __launch_bounds__(BQ, 4) void chamfer_min_kernel(
    const float* __restrict__ pred, const float* __restrict__ gt,
    int* __restrict__ minbuf,       // [2,B,N] f32-as-int running min of d2
    int N, int qtiles, int gchunks, int n_per_dir)
{
    int bid = blockIdx.x;
    int dir = bid / n_per_dir;          // 0: queries=gt, min over pred (z)
    int r   = bid - dir * n_per_dir;    // 1: queries=pred, min over gt (z2)
    int gc  = r % gchunks;
    int qt  = (r / gchunks) % qtiles;
    int b   = r / (gchunks * qtiles);

    const float* qpts = dir ? pred : gt;
    const float* opts = dir ? gt   : pred;
    int* mb = minbuf + (size_t)dir * 4 * N + (size_t)b * N;

    const float* qb = qpts + (size_t)b * 3 * N;
    const float* ob = opts + (size_t)b * 3 * N;

    // pair-transposed staging: ldsA[i] = {x_e, x_o, y_e, y_o},
    //                          ldsB[i] = {z_e, z_o, w_e, w_o}, w = -0.5|g|^2
    __shared__ float4 ldsA[GCHUNK / 2];
    __shared__ float4 ldsB[GCHUNK / 2];

    int gbase = gc * GCHUNK;
    for (int i = threadIdx.x; i < GCHUNK / 2; i += BQ) {
        int gi = gbase + 2 * i;
        float2 x2 = *(const float2*)(ob + gi);
        float2 y2 = *(const float2*)(ob + N + gi);
        float2 z2 = *(const float2*)(ob + 2 * N + gi);
        float we = -0.5f * fmaf(x2.x, x2.x, fmaf(y2.x, y2.x, z2.x * z2.x));
        float wo = -0.5f * fmaf(x2.y, x2.y, fmaf(y2.y, y2.y, z2.y * z2.y));
        ldsA[i] = make_float4(x2.x, x2.y, y2.x, y2.y);
        ldsB[i] = make_float4(z2.x, z2.y, we, wo);
    }
    __syncthreads();

    // query points in registers, broadcast into packed pairs
    v2f px2[QPT], py2[QPT], pz2[QPT];
    float qn[QPT], mx[QPT];
    int q0 = qt * QTILE + threadIdx.x;
    #pragma unroll
    for (int q = 0; q < QPT; ++q) {
        int qi = q0 + q * BQ;
        float px = qb[qi], py = qb[N + qi], pz = qb[2 * N + qi];
        px2[q] = (v2f){px, px};
        py2[q] = (v2f){py, py};
        pz2[q] = (v2f){pz, pz};
        qn[q] = fmaf(px, px, fmaf(py, py, pz * pz));
        mx[q] = -3.0e38f;
    }

    // main loop: 2 columns/step, uniform LDS address -> broadcast reads
    #pragma unroll 4
    for (int jp = 0; jp < GCHUNK / 2; ++jp) {
        float4 A  = ldsA[jp];
        float4 Bv = ldsB[jp];
        v2f xp = (v2f){A.x,  A.y };
        v2f yp = (v2f){A.z,  A.w };
        v2f zp = (v2f){Bv.x, Bv.y};
        v2f wp = (v2f){Bv.z, Bv.w};
        #pragma unroll
        for (int q = 0; q < QPT; ++q) {
            v2f s, t, u;
            PKFMA(s, pz2[q], zp, wp);
            PKFMA(t, py2[q], yp, s);
            PKFMA(u, px2[q], xp, t);
            mx[q] = fmaxf(mx[q], fmaxf(u.x, u.y));  // -> v_max3_f32
        }
    }

    // d2 = qn - 2*mx >= 0 (clamped); int-min on non-negative floats is exact
    #pragma unroll
    for (int q = 0; q < QPT; ++q) {
        float d2 = fmaxf(fmaf(-2.0f, mx[q], qn[q]), 0.0f);
        atomicMin(mb + q0 + q * BQ, __float_as_int(d2));
    }
}

__global__ __launch_bounds__(256) void chamfer_reduce1_kernel(
    const int* __restrict__ minbuf, float* __restrict__ partials, int per_blk)
{
    __shared__ float sdata[256];
    int base = blockIdx.x * per_blk + threadIdx.x;
    float s = 0.0f;
    for (int k = 0; k < per_blk; k += 256) {
        float d2 = __int_as_float(minbuf[base + k]);
        s += sqrtf(fmaxf(d2, 0.0f));
    }
    sdata[threadIdx.x] = s;
    __syncthreads();
    for (int off = 128; off > 0; off >>= 1) {
        if (threadIdx.x < off) sdata[threadIdx.x] += sdata[threadIdx.x + off];
        __syncthreads();
    }
    if (threadIdx.x == 0) partials[blockIdx.x] = sdata[0];
}

__global__ __launch_bounds__(64) void chamfer_reduce2_kernel(
    const float* __restrict__ partials, float* __restrict__ out, float inv_b)
{
    __shared__ float sdata[64];
    sdata[threadIdx.x] = partials[threadIdx.x];
    __syncthreads();
    for (int off = 32; off > 0; off >>= 1) {
        if (threadIdx.x < off) sdata[threadIdx.x] += sdata[threadIdx.x + off];
        __syncthreads();
    }
    if (threadIdx.x == 0) out[0] = sdata[0] * inv_b;
}

extern "C" void kernel_launch(void* const* d_in, const int* in_sizes, int n_in,
                              void* d_out, int out_size, void* d_ws, size_t ws_size,
                              hipStream_t stream) {
    const float* pred = (const float*)d_in[0];
    const float* gt   = (const float*)d_in[1];
    const int B = 4, D = 3;
    const int N = in_sizes[0] / (B * D);   // 8192
    const int total = 2 * B * N;           // 65536

    int* minbuf = (int*)d_ws;                          // 256 KB
    float* partials = (float*)((char*)d_ws + (size_t)total * sizeof(int));
    // 0x7F7F7F7F as float = 3.39e38 (positive) -> +inf sentinel
    hipMemsetAsync(d_ws, 0x7F, (size_t)total * sizeof(int), stream);

    int qtiles  = N / QTILE;    // 8
    int gchunks = N / GCHUNK;   // 32
    int n_per_dir = B * qtiles * gchunks;  // 1024
    chamfer_min_kernel<<<dim3(2 * n_per_dir), dim3(BQ), 0, stream>>>(
        pred, gt, minbuf, N, qtiles, gchunks, n_per_dir);

    chamfer_reduce1_kernel<<<dim3(RBLKS), dim3(256), 0, stream>>>(
        minbuf, partials, total / RBLKS);
    chamfer_reduce2_kernel<<<dim3(1), dim3(64), 0, stream>>>(
        partials, (float*)d_out, 1.0f / B);
}